// Round 6
// baseline (460.258 us; speedup 1.0000x reference)
//
#include <hip/hip_runtime.h>
#include <hip/hip_bf16.h>

#define B_IMG 4
#define PRE_NMS 4096
#define POST_NMS 500
#define CAND_CAP 8192
#define BND_CAP 65536
#define HBLK 256

typedef unsigned long long ull;

__device__ __forceinline__ unsigned key_of(float f) {
    unsigned u = __float_as_uint(f);
    return (u & 0x80000000u) ? ~u : (u | 0x80000000u);
}

// ---------------- pass-0 histogram (top byte), per-block partials ----------------
__global__ void hist0_kernel(const float* __restrict__ obj, unsigned* __restrict__ histPart, int A) {
    int b = blockIdx.y;
    __shared__ unsigned h[4][256];
    int t = threadIdx.x;
#pragma unroll
    for (int r = 0; r < 4; r++) h[r][t] = 0u;
    __syncthreads();
    const float4* o4 = (const float4*)(obj + (size_t)b * A);
    int n4 = A >> 2;
    int stride = gridDim.x * blockDim.x;
    int rep = t & 3;
    for (int i = blockIdx.x * blockDim.x + t; i < n4; i += stride) {
        float4 v = o4[i];
        atomicAdd(&h[rep][key_of(v.x) >> 24], 1u);
        atomicAdd(&h[rep][key_of(v.y) >> 24], 1u);
        atomicAdd(&h[rep][key_of(v.z) >> 24], 1u);
        atomicAdd(&h[rep][key_of(v.w) >> 24], 1u);
    }
    if (blockIdx.x == 0 && t < (A & 3)) {
        unsigned k = key_of(obj[(size_t)b * A + (A & ~3) + t]);
        atomicAdd(&h[rep][k >> 24], 1u);
    }
    __syncthreads();
    histPart[((size_t)b * HBLK + blockIdx.x) * 256 + t] = h[0][t] + h[1][t] + h[2][t] + h[3][t];
}

// ---------------- pass-0 reduce + boundary scan; zero counters ----------------
__global__ void scan0_kernel(uint2* state, const unsigned* __restrict__ histPart,
                             unsigned* __restrict__ count) {
    int b = blockIdx.x;
    int t = threadIdx.x;  // 256
    __shared__ unsigned h[256];
    unsigned s = 0;
    for (int blk = 0; blk < HBLK; blk++) s += histPart[((size_t)b * HBLK + blk) * 256 + t];
    h[t] = s;
    __syncthreads();
    if (t == 0) {
        unsigned kneed = PRE_NMS, cum = 0;
        int d;
        for (d = 255; d > 0; d--) {
            unsigned c = h[d];
            if (cum + c >= kneed) break;
            cum += c;
        }
        state[b] = make_uint2((unsigned)d, kneed - cum);
        count[b] = 0u;
        count[B_IMG + b] = 0u;
    }
}

// ---------------- compact: emit all elements with top byte >= d0 ----------------
__global__ void compact_kernel(const float* __restrict__ obj, const uint2* __restrict__ state,
                               ull* __restrict__ bnd, unsigned* __restrict__ count, int A) {
    int b = blockIdx.y;
    unsigned d0 = state[b].x;
    __shared__ ull buf[2048];
    __shared__ unsigned lcnt, base;
    int t = threadIdx.x;
    if (t == 0) lcnt = 0u;
    __syncthreads();
    const float4* o4 = (const float4*)(obj + (size_t)b * A);
    int n4 = A >> 2;
    int stride = gridDim.x * blockDim.x;
    for (int i = blockIdx.x * blockDim.x + t; i < n4; i += stride) {
        float4 v = o4[i];
        unsigned i0 = (unsigned)i * 4u;
        unsigned k0 = key_of(v.x), k1 = key_of(v.y), k2 = key_of(v.z), k3 = key_of(v.w);
        if ((k0 >> 24) >= d0) { unsigned p = atomicAdd(&lcnt, 1u); if (p < 2048u) buf[p] = ((ull)k0 << 32) | (0xFFFFFFFFu - i0); }
        if ((k1 >> 24) >= d0) { unsigned p = atomicAdd(&lcnt, 1u); if (p < 2048u) buf[p] = ((ull)k1 << 32) | (0xFFFFFFFFu - (i0 + 1u)); }
        if ((k2 >> 24) >= d0) { unsigned p = atomicAdd(&lcnt, 1u); if (p < 2048u) buf[p] = ((ull)k2 << 32) | (0xFFFFFFFFu - (i0 + 2u)); }
        if ((k3 >> 24) >= d0) { unsigned p = atomicAdd(&lcnt, 1u); if (p < 2048u) buf[p] = ((ull)k3 << 32) | (0xFFFFFFFFu - (i0 + 3u)); }
    }
    if (blockIdx.x == 0 && t < (A & 3)) {
        unsigned ii = (unsigned)(A & ~3) + t;
        unsigned k = key_of(obj[(size_t)b * A + ii]);
        if ((k >> 24) >= d0) { unsigned p = atomicAdd(&lcnt, 1u); if (p < 2048u) buf[p] = ((ull)k << 32) | (0xFFFFFFFFu - ii); }
    }
    __syncthreads();
    unsigned c = lcnt < 2048u ? lcnt : 2048u;
    if (t == 0) base = atomicAdd(&count[B_IMG + b], c);
    __syncthreads();
    for (unsigned p = t; p < c; p += blockDim.x) {
        unsigned pos = base + p;
        if (pos < BND_CAP) bnd[(size_t)b * BND_CAP + pos] = buf[p];
    }
}

// ---------------- refine: radix passes 1-3 + threshold gather + zero-pad ----------------
__global__ void __launch_bounds__(1024) refine_kernel(const ull* __restrict__ bnd,
                                                      const uint2* __restrict__ state,
                                                      ull* __restrict__ cand,
                                                      unsigned* __restrict__ count) {
    int b = blockIdx.x;
    __shared__ unsigned h[256];
    __shared__ unsigned sh_prefix, sh_kneed, sh_pos;
    int t = threadIdx.x;
    unsigned n = count[B_IMG + b];
    if (n > BND_CAP) n = BND_CAP;
    const ull* L = bnd + (size_t)b * BND_CAP;
    if (t == 0) { sh_prefix = state[b].x; sh_kneed = state[b].y; sh_pos = 0u; }
    for (int pass = 1; pass < 4; pass++) {
        if (t < 256) h[t] = 0u;
        __syncthreads();
        unsigned prefix = sh_prefix;
        int sh = 32 - 8 * pass, dsh = 24 - 8 * pass;
        for (unsigned i = t; i < n; i += 1024) {
            unsigned key = (unsigned)(L[i] >> 32);
            if ((key >> sh) == prefix) atomicAdd(&h[(key >> dsh) & 255u], 1u);
        }
        __syncthreads();
        if (t == 0) {
            unsigned kneed = sh_kneed, cum = 0;
            int d;
            for (d = 255; d > 0; d--) {
                unsigned c = h[d];
                if (cum + c >= kneed) break;
                cum += c;
            }
            sh_prefix = (prefix << 8) | (unsigned)d;
            sh_kneed = kneed - cum;
        }
        __syncthreads();
    }
    unsigned T = sh_prefix;
    for (unsigned i = t; i < n; i += 1024) {
        ull v = L[i];
        if ((unsigned)(v >> 32) >= T) {
            unsigned p = atomicAdd(&sh_pos, 1u);
            if (p < CAND_CAP) cand[(size_t)b * (CAND_CAP + 8) + p] = v;
        }
    }
    __syncthreads();
    if (t < 8) {
        unsigned cc = sh_pos < CAND_CAP ? sh_pos : CAND_CAP;
        cand[(size_t)b * (CAND_CAP + 8) + cc + t] = 0ull;  // zero-pad for rank's 8-unroll
        if (t == 0) count[b] = cc;
    }
}

// ---------------- rank + decode fused ----------------
// rank = #{j: comp[j] > comp[i]} (composites unique -> exact stable-sort position).
// Thread then decodes its box directly at position `rank`. obj recovered
// bit-exactly by inverting the monotone key. Kills the topk/decode round-trip.
__global__ void __launch_bounds__(256) rankdecode_kernel(
        const ull* __restrict__ cand, const unsigned* __restrict__ count,
        const float* __restrict__ anchors, const float* __restrict__ reg,
        float* __restrict__ boxes, float* __restrict__ X1, float* __restrict__ X2,
        float* __restrict__ Y1, float* __restrict__ Y2, float* __restrict__ AREA,
        float* __restrict__ s_top, int A) {
    int b = blockIdx.y;
    unsigned cnt = count[b];
    if (cnt > CAND_CAP) cnt = CAND_CAP;
    unsigned c = blockIdx.x * 256 + threadIdx.x;
    if (c >= cnt) return;
    const ull* C = cand + (size_t)b * (CAND_CAP + 8);
    ull me = C[c];
    unsigned cntR = (cnt + 7u) & ~7u;
    unsigned rank = 0;
    for (unsigned j = 0; j < cntR; j += 8) {
        rank += (unsigned)(C[j]     > me) + (unsigned)(C[j + 1] > me)
              + (unsigned)(C[j + 2] > me) + (unsigned)(C[j + 3] > me)
              + (unsigned)(C[j + 4] > me) + (unsigned)(C[j + 5] > me)
              + (unsigned)(C[j + 6] > me) + (unsigned)(C[j + 7] > me);
    }
    if (rank >= PRE_NMS) return;
    unsigned key = (unsigned)(me >> 32);
    unsigned idx = 0xFFFFFFFFu - (unsigned)(me & 0xFFFFFFFFull);
    unsigned ub = (key & 0x80000000u) ? (key & 0x7FFFFFFFu) : ~key;
    float x = __uint_as_float(ub);
    s_top[b * PRE_NMS + rank] = 1.0f / (1.0f + expf(-x));
    const float* an = anchors + ((size_t)b * A + idx) * 7;
    const float* rg = reg + ((size_t)b * A + idx) * 7;
    float xa = an[0], ya = an[1], za = an[2], wa = an[3], la = an[4], ha = an[5], ra = an[6];
    float diagv = sqrtf(wa * wa + la * la);
    float xg = rg[0] * diagv + xa;
    float yg = rg[1] * diagv + ya;
    float zg = rg[2] * ha + za;
    float wg = expf(rg[3]) * wa;
    float lg = expf(rg[4]) * la;
    float hg = expf(rg[5]) * ha;
    float rr = rg[6] + ra;
    float* o = boxes + ((size_t)b * PRE_NMS + rank) * 7;
    o[0] = xg; o[1] = yg; o[2] = zg; o[3] = wg; o[4] = lg; o[5] = hg; o[6] = rr;
    int q = b * PRE_NMS + rank;
    X1[q] = xg - wg * 0.5f;
    X2[q] = xg + wg * 0.5f;
    Y1[q] = yg - lg * 0.5f;
    Y2[q] = yg + lg * 0.5f;
    AREA[q] = wg * lg;
}

// ---------------- suppression bitmask (triangular early-out) ----------------
__global__ void mask_kernel(const float* __restrict__ X1, const float* __restrict__ X2,
                            const float* __restrict__ Y1, const float* __restrict__ Y2,
                            const float* __restrict__ AREA, ull* __restrict__ mask) {
    int b = blockIdx.y;
    int t = blockIdx.x * 256 + threadIdx.x;
    int i = t & (PRE_NMS - 1);
    int w = t >> 12;
    size_t mi = ((size_t)b * PRE_NMS + i) * 64 + w;
    if (i >= ((w + 1) << 6)) { mask[mi] = 0ull; return; }  // all j<=i -> word is 0
    int q0 = b * PRE_NMS;
    float x1i = X1[q0 + i], x2i = X2[q0 + i];
    float y1i = Y1[q0 + i], y2i = Y2[q0 + i];
    float ai = AREA[q0 + i];
    ull word = 0ull;
    int jbase = w << 6;
#pragma unroll 4
    for (int k = 0; k < 64; k++) {
        int j = jbase + k;
        float iw = fminf(x2i, X2[q0 + j]) - fmaxf(x1i, X1[q0 + j]);
        iw = fmaxf(iw, 0.0f);
        float ih = fminf(y2i, Y2[q0 + j]) - fmaxf(y1i, Y1[q0 + j]);
        ih = fmaxf(ih, 0.0f);
        float inter = iw * ih;
        float den = ai + AREA[q0 + j] - inter + 1e-6f;
        float iou = inter / den;
        word |= ((ull)((iou > 0.7f) && (j > i))) << k;
    }
    mask[mi] = word;
}

// ---------------- 4-wave cooperative NMS + select + write ----------------
// Lane owns keep word `lane` (K replicated across waves). Wave v owns rows
// [16v,16v+16) of each 64-row tile, held in registers with a depth-4 static
// pipeline (prefetch tile w+4 while computing w). Per tile: diagonal words ->
// LDS (parity buffered), replicated greedy resolve, partial OR -> LDS, merge.
__global__ void __launch_bounds__(256, 1) nms_select_kernel(
        const ull* __restrict__ mask, const float* __restrict__ boxes,
        const float* __restrict__ s_top, float* __restrict__ out) {
    int b = blockIdx.x;
    int t = threadIdx.x;
    int lane = t & 63, v = t >> 6;
    int rbase = v * 16;
    const ull* Mb = mask + (size_t)b * PRE_NMS * 64;
    __shared__ ull diag[2][64];
    __shared__ ull part[2][4][64];
    __shared__ ull keepw[64];
    __shared__ int cnts[64];
    __shared__ int bases[65];
    __shared__ int sel[POST_NMS];
    ull K = ~0ull;
    ull b0[16], b1[16], b2[16], b3[16];

#define PREF(W, BUF) do {                                                          \
    _Pragma("unroll")                                                              \
    for (int kk = 0; kk < 16; kk++)                                                \
        BUF[kk] = Mb[(((size_t)(W) * 64 + rbase + kk) << 6) + lane];               \
} while (0)

#define TILE(W, BUF) do {                                                          \
    int par = (W) & 1;                                                             \
    ull cur = __shfl(K, (W));                                                      \
    if (lane == (W)) {                                                             \
        _Pragma("unroll")                                                          \
        for (int kk = 0; kk < 16; kk++) diag[par][rbase + kk] = BUF[kk];           \
    }                                                                              \
    __syncthreads();                                                               \
    ull dl = diag[par][lane];                                                      \
    ull active = __ballot(dl != 0ull) & cur;                                       \
    while (active) {                                                               \
        int kk = __ffsll((long long)active) - 1;                                   \
        ull dk = __shfl(dl, kk);                                                   \
        cur &= ~dk; active &= ~dk; active &= ~(1ull << kk);                        \
    }                                                                              \
    ull sup = 0ull;                                                                \
    _Pragma("unroll")                                                              \
    for (int kk = 0; kk < 16; kk++)                                                \
        sup |= ((cur >> (rbase + kk)) & 1ull) ? BUF[kk] : 0ull;                    \
    part[par][v][lane] = sup;                                                      \
    __syncthreads();                                                               \
    K &= ~(part[par][0][lane] | part[par][1][lane] |                               \
           part[par][2][lane] | part[par][3][lane]);                               \
    if ((W) + 4 < 64) {                                                            \
        _Pragma("unroll")                                                          \
        for (int kk = 0; kk < 16; kk++)                                            \
            BUF[kk] = Mb[((((size_t)(W) + 4) * 64 + rbase + kk) << 6) + lane];     \
    }                                                                              \
} while (0)

    PREF(0, b0); PREF(1, b1); PREF(2, b2); PREF(3, b3);
    for (int w = 0; w < 64; w += 4) {
        TILE(w + 0, b0);
        TILE(w + 1, b1);
        TILE(w + 2, b2);
        TILE(w + 3, b3);
    }
#undef PREF
#undef TILE

    if (v == 0) keepw[lane] = K;
    __syncthreads();
    if (t < 64) cnts[t] = __popcll(keepw[t]);
    __syncthreads();
    if (t == 0) {
        int acc = 0;
        for (int w = 0; w < 64; w++) { bases[w] = acc; acc += cnts[w]; }
        bases[64] = acc;
    }
    __syncthreads();
    if (t < 64) {
        ull kw = keepw[t];
        int K_total = bases[64];
        int kr = bases[t];
        int ur = t * 64 - bases[t];
        for (int k = 0; k < 64; k++) {
            int i = t * 64 + k;
            if ((kw >> k) & 1ull) {
                if (kr < POST_NMS) sel[kr] = i;
                kr++;
            } else {
                int pos = K_total + ur;
                if (pos < POST_NMS) sel[pos] = i;
                ur++;
            }
        }
    }
    __syncthreads();
    for (int r = t; r < POST_NMS; r += 256) {
        int i = sel[r];
        const float* bx = boxes + ((size_t)b * PRE_NMS + i) * 7;
        float* o = out + ((size_t)b * POST_NMS + r) * 8;
#pragma unroll
        for (int c = 0; c < 7; c++) o[c] = bx[c];
        o[7] = s_top[b * PRE_NMS + i];
    }
}

extern "C" void kernel_launch(void* const* d_in, const int* in_sizes, int n_in,
                              void* d_out, int out_size, void* d_ws, size_t ws_size,
                              hipStream_t stream) {
    const float* anchors = (const float*)d_in[0];
    const float* obj = (const float*)d_in[1];
    const float* reg = (const float*)d_in[2];
    float* out = (float*)d_out;
    const int A = in_sizes[1] / B_IMG;

    auto align = [](size_t x) { return (x + 255) & ~(size_t)255; };
    char* p = (char*)d_ws;
    uint2* state = (uint2*)p;       p += align(B_IMG * sizeof(uint2));
    unsigned* histPart = (unsigned*)p; p += align((size_t)B_IMG * HBLK * 256 * 4);
    unsigned* count = (unsigned*)p; p += align(2 * B_IMG * sizeof(unsigned));
    ull* cand = (ull*)p;            p += align((size_t)B_IMG * (CAND_CAP + 8) * 8);
    ull* bnd = (ull*)p;             p += align((size_t)B_IMG * BND_CAP * 8);
    float* s_top = (float*)p;       p += align((size_t)B_IMG * PRE_NMS * 4);
    float* boxes = (float*)p;       p += align((size_t)B_IMG * PRE_NMS * 7 * 4);
    float* X1 = (float*)p;          p += align((size_t)B_IMG * PRE_NMS * 4);
    float* X2 = (float*)p;          p += align((size_t)B_IMG * PRE_NMS * 4);
    float* Y1 = (float*)p;          p += align((size_t)B_IMG * PRE_NMS * 4);
    float* Y2 = (float*)p;          p += align((size_t)B_IMG * PRE_NMS * 4);
    float* AREA = (float*)p;        p += align((size_t)B_IMG * PRE_NMS * 4);
    ull* mask = (ull*)p;            p += align((size_t)B_IMG * PRE_NMS * 64 * 8);

    hist0_kernel<<<dim3(HBLK, B_IMG), 256, 0, stream>>>(obj, histPart, A);
    scan0_kernel<<<B_IMG, 256, 0, stream>>>(state, histPart, count);
    compact_kernel<<<dim3(HBLK, B_IMG), 256, 0, stream>>>(obj, state, bnd, count, A);
    refine_kernel<<<B_IMG, 1024, 0, stream>>>(bnd, state, cand, count);
    rankdecode_kernel<<<dim3(CAND_CAP / 256, B_IMG), 256, 0, stream>>>(
        cand, count, anchors, reg, boxes, X1, X2, Y1, Y2, AREA, s_top, A);
    mask_kernel<<<dim3(PRE_NMS * 64 / 256, B_IMG), 256, 0, stream>>>(X1, X2, Y1, Y2, AREA, mask);
    nms_select_kernel<<<B_IMG, 256, 0, stream>>>(mask, boxes, s_top, out);
}

// Round 7
// 369.618 us; speedup vs baseline: 1.2452x; 1.2452x over previous
//
#include <hip/hip_runtime.h>
#include <hip/hip_bf16.h>

#define B_IMG 4
#define PRE_NMS 4096
#define POST_NMS 500
#define CAND_CAP 8192
#define BND_CAP 65536
#define HBLK 256

typedef unsigned long long ull;

__device__ __forceinline__ unsigned key_of(float f) {
    unsigned u = __float_as_uint(f);
    return (u & 0x80000000u) ? ~u : (u | 0x80000000u);
}

// ---------------- pass-0 histogram (top byte), per-block partials ----------------
__global__ void hist0_kernel(const float* __restrict__ obj, unsigned* __restrict__ histPart, int A) {
    int b = blockIdx.y;
    __shared__ unsigned h[4][256];
    int t = threadIdx.x;
#pragma unroll
    for (int r = 0; r < 4; r++) h[r][t] = 0u;
    __syncthreads();
    const float4* o4 = (const float4*)(obj + (size_t)b * A);
    int n4 = A >> 2;
    int stride = gridDim.x * blockDim.x;
    int rep = t & 3;
    for (int i = blockIdx.x * blockDim.x + t; i < n4; i += stride) {
        float4 v = o4[i];
        atomicAdd(&h[rep][key_of(v.x) >> 24], 1u);
        atomicAdd(&h[rep][key_of(v.y) >> 24], 1u);
        atomicAdd(&h[rep][key_of(v.z) >> 24], 1u);
        atomicAdd(&h[rep][key_of(v.w) >> 24], 1u);
    }
    if (blockIdx.x == 0 && t < (A & 3)) {
        unsigned k = key_of(obj[(size_t)b * A + (A & ~3) + t]);
        atomicAdd(&h[rep][k >> 24], 1u);
    }
    __syncthreads();
    histPart[((size_t)b * HBLK + blockIdx.x) * 256 + t] = h[0][t] + h[1][t] + h[2][t] + h[3][t];
}

// ---------------- pass-0 reduce + boundary scan; zero counters ----------------
__global__ void scan0_kernel(uint2* state, const unsigned* __restrict__ histPart,
                             unsigned* __restrict__ count) {
    int b = blockIdx.x;
    int t = threadIdx.x;  // 256
    __shared__ unsigned h[256];
    unsigned s = 0;
    for (int blk = 0; blk < HBLK; blk++) s += histPart[((size_t)b * HBLK + blk) * 256 + t];
    h[t] = s;
    __syncthreads();
    if (t == 0) {
        unsigned kneed = PRE_NMS, cum = 0;
        int d;
        for (d = 255; d > 0; d--) {
            unsigned c = h[d];
            if (cum + c >= kneed) break;
            cum += c;
        }
        state[b] = make_uint2((unsigned)d, kneed - cum);
        count[b] = 0u;
        count[B_IMG + b] = 0u;
    }
}

// ---------------- compact: emit all elements with top byte >= d0 ----------------
__global__ void compact_kernel(const float* __restrict__ obj, const uint2* __restrict__ state,
                               ull* __restrict__ bnd, unsigned* __restrict__ count, int A) {
    int b = blockIdx.y;
    unsigned d0 = state[b].x;
    __shared__ ull buf[2048];
    __shared__ unsigned lcnt, base;
    int t = threadIdx.x;
    if (t == 0) lcnt = 0u;
    __syncthreads();
    const float4* o4 = (const float4*)(obj + (size_t)b * A);
    int n4 = A >> 2;
    int stride = gridDim.x * blockDim.x;
    for (int i = blockIdx.x * blockDim.x + t; i < n4; i += stride) {
        float4 v = o4[i];
        unsigned i0 = (unsigned)i * 4u;
        unsigned k0 = key_of(v.x), k1 = key_of(v.y), k2 = key_of(v.z), k3 = key_of(v.w);
        if ((k0 >> 24) >= d0) { unsigned p = atomicAdd(&lcnt, 1u); if (p < 2048u) buf[p] = ((ull)k0 << 32) | (0xFFFFFFFFu - i0); }
        if ((k1 >> 24) >= d0) { unsigned p = atomicAdd(&lcnt, 1u); if (p < 2048u) buf[p] = ((ull)k1 << 32) | (0xFFFFFFFFu - (i0 + 1u)); }
        if ((k2 >> 24) >= d0) { unsigned p = atomicAdd(&lcnt, 1u); if (p < 2048u) buf[p] = ((ull)k2 << 32) | (0xFFFFFFFFu - (i0 + 2u)); }
        if ((k3 >> 24) >= d0) { unsigned p = atomicAdd(&lcnt, 1u); if (p < 2048u) buf[p] = ((ull)k3 << 32) | (0xFFFFFFFFu - (i0 + 3u)); }
    }
    if (blockIdx.x == 0 && t < (A & 3)) {
        unsigned ii = (unsigned)(A & ~3) + t;
        unsigned k = key_of(obj[(size_t)b * A + ii]);
        if ((k >> 24) >= d0) { unsigned p = atomicAdd(&lcnt, 1u); if (p < 2048u) buf[p] = ((ull)k << 32) | (0xFFFFFFFFu - ii); }
    }
    __syncthreads();
    unsigned c = lcnt < 2048u ? lcnt : 2048u;
    if (t == 0) base = atomicAdd(&count[B_IMG + b], c);
    __syncthreads();
    for (unsigned p = t; p < c; p += blockDim.x) {
        unsigned pos = base + p;
        if (pos < BND_CAP) bnd[(size_t)b * BND_CAP + pos] = buf[p];
    }
}

// ---------------- refine: radix passes 1-3 + threshold gather + zero-pad ----------------
__global__ void __launch_bounds__(1024) refine_kernel(const ull* __restrict__ bnd,
                                                      const uint2* __restrict__ state,
                                                      ull* __restrict__ cand,
                                                      unsigned* __restrict__ count) {
    int b = blockIdx.x;
    __shared__ unsigned h[256];
    __shared__ unsigned sh_prefix, sh_kneed, sh_pos;
    int t = threadIdx.x;
    unsigned n = count[B_IMG + b];
    if (n > BND_CAP) n = BND_CAP;
    const ull* L = bnd + (size_t)b * BND_CAP;
    if (t == 0) { sh_prefix = state[b].x; sh_kneed = state[b].y; sh_pos = 0u; }
    for (int pass = 1; pass < 4; pass++) {
        if (t < 256) h[t] = 0u;
        __syncthreads();
        unsigned prefix = sh_prefix;
        int sh = 32 - 8 * pass, dsh = 24 - 8 * pass;
        for (unsigned i = t; i < n; i += 1024) {
            unsigned key = (unsigned)(L[i] >> 32);
            if ((key >> sh) == prefix) atomicAdd(&h[(key >> dsh) & 255u], 1u);
        }
        __syncthreads();
        if (t == 0) {
            unsigned kneed = sh_kneed, cum = 0;
            int d;
            for (d = 255; d > 0; d--) {
                unsigned c = h[d];
                if (cum + c >= kneed) break;
                cum += c;
            }
            sh_prefix = (prefix << 8) | (unsigned)d;
            sh_kneed = kneed - cum;
        }
        __syncthreads();
    }
    unsigned T = sh_prefix;
    for (unsigned i = t; i < n; i += 1024) {
        ull v = L[i];
        if ((unsigned)(v >> 32) >= T) {
            unsigned p = atomicAdd(&sh_pos, 1u);
            if (p < CAND_CAP) cand[(size_t)b * (CAND_CAP + 16) + p] = v;
        }
    }
    __syncthreads();
    if (t < 16) {
        unsigned cc = sh_pos < CAND_CAP ? sh_pos : CAND_CAP;
        cand[(size_t)b * (CAND_CAP + 16) + cc + t] = 0ull;  // zero-pad for rank's 16-unroll
        if (t == 0) count[b] = cc;
    }
}

// ---------------- rank + decode fused (LDS-staged) ----------------
// rank = #{j: comp[j] > comp[i]} (composites unique -> exact stable-sort position).
// Candidates staged once in LDS; inner loop is broadcast ds_read_b128 pairs
// (same-address across lanes = conflict-free). Thread with rank<PRE_NMS decodes
// its box directly at position rank; obj recovered bit-exactly from the key.
__global__ void __launch_bounds__(256) rankdecode_kernel(
        const ull* __restrict__ cand, const unsigned* __restrict__ count,
        const float* __restrict__ anchors, const float* __restrict__ reg,
        float* __restrict__ boxes, float* __restrict__ X1, float* __restrict__ X2,
        float* __restrict__ Y1, float* __restrict__ Y2, float* __restrict__ AREA,
        float* __restrict__ s_top, int A) {
    __shared__ ull s[CAND_CAP];
    int b = blockIdx.y;
    unsigned cnt = count[b];
    if (cnt > CAND_CAP) cnt = CAND_CAP;
    if (blockIdx.x * 256 >= cnt) return;          // uniform: whole block idle
    int t = threadIdx.x;
    const ull* C = cand + (size_t)b * (CAND_CAP + 16);
    unsigned cntR = (cnt + 15u) & ~15u;           // pad covered by 16 zero-pads
    for (unsigned i = t; i < cntR; i += 256) s[i] = C[i];
    __syncthreads();
    unsigned c = blockIdx.x * 256 + t;
    if (c >= cnt) return;
    ull me = s[c];
    unsigned rank = 0;
    for (unsigned j = 0; j < cntR; j += 16) {
#pragma unroll
        for (int k = 0; k < 16; k++) rank += (unsigned)(s[j + k] > me);
    }
    if (rank >= PRE_NMS) return;
    unsigned key = (unsigned)(me >> 32);
    unsigned idx = 0xFFFFFFFFu - (unsigned)(me & 0xFFFFFFFFull);
    unsigned ub = (key & 0x80000000u) ? (key & 0x7FFFFFFFu) : ~key;
    float x = __uint_as_float(ub);
    s_top[b * PRE_NMS + rank] = 1.0f / (1.0f + expf(-x));
    const float* an = anchors + ((size_t)b * A + idx) * 7;
    const float* rg = reg + ((size_t)b * A + idx) * 7;
    float xa = an[0], ya = an[1], za = an[2], wa = an[3], la = an[4], ha = an[5], ra = an[6];
    float diagv = sqrtf(wa * wa + la * la);
    float xg = rg[0] * diagv + xa;
    float yg = rg[1] * diagv + ya;
    float zg = rg[2] * ha + za;
    float wg = expf(rg[3]) * wa;
    float lg = expf(rg[4]) * la;
    float hg = expf(rg[5]) * ha;
    float rr = rg[6] + ra;
    float* o = boxes + ((size_t)b * PRE_NMS + rank) * 7;
    o[0] = xg; o[1] = yg; o[2] = zg; o[3] = wg; o[4] = lg; o[5] = hg; o[6] = rr;
    int q = b * PRE_NMS + rank;
    X1[q] = xg - wg * 0.5f;
    X2[q] = xg + wg * 0.5f;
    Y1[q] = yg - lg * 0.5f;
    Y2[q] = yg + lg * 0.5f;
    AREA[q] = wg * lg;
}

// ---------------- suppression bitmask (triangular early-out) ----------------
__global__ void mask_kernel(const float* __restrict__ X1, const float* __restrict__ X2,
                            const float* __restrict__ Y1, const float* __restrict__ Y2,
                            const float* __restrict__ AREA, ull* __restrict__ mask) {
    int b = blockIdx.y;
    int t = blockIdx.x * 256 + threadIdx.x;
    int i = t & (PRE_NMS - 1);
    int w = t >> 12;
    size_t mi = ((size_t)b * PRE_NMS + i) * 64 + w;
    if (i >= ((w + 1) << 6)) { mask[mi] = 0ull; return; }  // all j<=i -> word is 0
    int q0 = b * PRE_NMS;
    float x1i = X1[q0 + i], x2i = X2[q0 + i];
    float y1i = Y1[q0 + i], y2i = Y2[q0 + i];
    float ai = AREA[q0 + i];
    ull word = 0ull;
    int jbase = w << 6;
#pragma unroll 4
    for (int k = 0; k < 64; k++) {
        int j = jbase + k;
        float iw = fminf(x2i, X2[q0 + j]) - fmaxf(x1i, X1[q0 + j]);
        iw = fmaxf(iw, 0.0f);
        float ih = fminf(y2i, Y2[q0 + j]) - fmaxf(y1i, Y1[q0 + j]);
        ih = fmaxf(ih, 0.0f);
        float inter = iw * ih;
        float den = ai + AREA[q0 + j] - inter + 1e-6f;
        float iou = inter / den;
        word |= ((ull)((iou > 0.7f) && (j > i))) << k;
    }
    mask[mi] = word;
}

// ---------------- 4-wave cooperative NMS + select + write ----------------
__global__ void __launch_bounds__(256, 1) nms_select_kernel(
        const ull* __restrict__ mask, const float* __restrict__ boxes,
        const float* __restrict__ s_top, float* __restrict__ out) {
    int b = blockIdx.x;
    int t = threadIdx.x;
    int lane = t & 63, v = t >> 6;
    int rbase = v * 16;
    const ull* Mb = mask + (size_t)b * PRE_NMS * 64;
    __shared__ ull diag[2][64];
    __shared__ ull part[2][4][64];
    __shared__ ull keepw[64];
    __shared__ int cnts[64];
    __shared__ int bases[65];
    __shared__ int sel[POST_NMS];
    ull K = ~0ull;
    ull b0[16], b1[16], b2[16], b3[16];

#define PREF(W, BUF) do {                                                          \
    _Pragma("unroll")                                                              \
    for (int kk = 0; kk < 16; kk++)                                                \
        BUF[kk] = Mb[(((size_t)(W) * 64 + rbase + kk) << 6) + lane];               \
} while (0)

#define TILE(W, BUF) do {                                                          \
    int par = (W) & 1;                                                             \
    ull cur = __shfl(K, (W));                                                      \
    if (lane == (W)) {                                                             \
        _Pragma("unroll")                                                          \
        for (int kk = 0; kk < 16; kk++) diag[par][rbase + kk] = BUF[kk];           \
    }                                                                              \
    __syncthreads();                                                               \
    ull dl = diag[par][lane];                                                      \
    ull active = __ballot(dl != 0ull) & cur;                                       \
    while (active) {                                                               \
        int kk = __ffsll((long long)active) - 1;                                   \
        ull dk = __shfl(dl, kk);                                                   \
        cur &= ~dk; active &= ~dk; active &= ~(1ull << kk);                        \
    }                                                                              \
    ull sup = 0ull;                                                                \
    _Pragma("unroll")                                                              \
    for (int kk = 0; kk < 16; kk++)                                                \
        sup |= ((cur >> (rbase + kk)) & 1ull) ? BUF[kk] : 0ull;                    \
    part[par][v][lane] = sup;                                                      \
    __syncthreads();                                                               \
    K &= ~(part[par][0][lane] | part[par][1][lane] |                               \
           part[par][2][lane] | part[par][3][lane]);                               \
    if ((W) + 4 < 64) {                                                            \
        _Pragma("unroll")                                                          \
        for (int kk = 0; kk < 16; kk++)                                            \
            BUF[kk] = Mb[((((size_t)(W) + 4) * 64 + rbase + kk) << 6) + lane];     \
    }                                                                              \
} while (0)

    PREF(0, b0); PREF(1, b1); PREF(2, b2); PREF(3, b3);
    for (int w = 0; w < 64; w += 4) {
        TILE(w + 0, b0);
        TILE(w + 1, b1);
        TILE(w + 2, b2);
        TILE(w + 3, b3);
    }
#undef PREF
#undef TILE

    if (v == 0) keepw[lane] = K;
    __syncthreads();
    if (t < 64) cnts[t] = __popcll(keepw[t]);
    __syncthreads();
    if (t == 0) {
        int acc = 0;
        for (int w = 0; w < 64; w++) { bases[w] = acc; acc += cnts[w]; }
        bases[64] = acc;
    }
    __syncthreads();
    if (t < 64) {
        ull kw = keepw[t];
        int K_total = bases[64];
        int kr = bases[t];
        int ur = t * 64 - bases[t];
        for (int k = 0; k < 64; k++) {
            int i = t * 64 + k;
            if ((kw >> k) & 1ull) {
                if (kr < POST_NMS) sel[kr] = i;
                kr++;
            } else {
                int pos = K_total + ur;
                if (pos < POST_NMS) sel[pos] = i;
                ur++;
            }
        }
    }
    __syncthreads();
    for (int r = t; r < POST_NMS; r += 256) {
        int i = sel[r];
        const float* bx = boxes + ((size_t)b * PRE_NMS + i) * 7;
        float* o = out + ((size_t)b * POST_NMS + r) * 8;
#pragma unroll
        for (int c = 0; c < 7; c++) o[c] = bx[c];
        o[7] = s_top[b * PRE_NMS + i];
    }
}

extern "C" void kernel_launch(void* const* d_in, const int* in_sizes, int n_in,
                              void* d_out, int out_size, void* d_ws, size_t ws_size,
                              hipStream_t stream) {
    const float* anchors = (const float*)d_in[0];
    const float* obj = (const float*)d_in[1];
    const float* reg = (const float*)d_in[2];
    float* out = (float*)d_out;
    const int A = in_sizes[1] / B_IMG;

    auto align = [](size_t x) { return (x + 255) & ~(size_t)255; };
    char* p = (char*)d_ws;
    uint2* state = (uint2*)p;       p += align(B_IMG * sizeof(uint2));
    unsigned* histPart = (unsigned*)p; p += align((size_t)B_IMG * HBLK * 256 * 4);
    unsigned* count = (unsigned*)p; p += align(2 * B_IMG * sizeof(unsigned));
    ull* cand = (ull*)p;            p += align((size_t)B_IMG * (CAND_CAP + 16) * 8);
    ull* bnd = (ull*)p;             p += align((size_t)B_IMG * BND_CAP * 8);
    float* s_top = (float*)p;       p += align((size_t)B_IMG * PRE_NMS * 4);
    float* boxes = (float*)p;       p += align((size_t)B_IMG * PRE_NMS * 7 * 4);
    float* X1 = (float*)p;          p += align((size_t)B_IMG * PRE_NMS * 4);
    float* X2 = (float*)p;          p += align((size_t)B_IMG * PRE_NMS * 4);
    float* Y1 = (float*)p;          p += align((size_t)B_IMG * PRE_NMS * 4);
    float* Y2 = (float*)p;          p += align((size_t)B_IMG * PRE_NMS * 4);
    float* AREA = (float*)p;        p += align((size_t)B_IMG * PRE_NMS * 4);
    ull* mask = (ull*)p;            p += align((size_t)B_IMG * PRE_NMS * 64 * 8);

    hist0_kernel<<<dim3(HBLK, B_IMG), 256, 0, stream>>>(obj, histPart, A);
    scan0_kernel<<<B_IMG, 256, 0, stream>>>(state, histPart, count);
    compact_kernel<<<dim3(HBLK, B_IMG), 256, 0, stream>>>(obj, state, bnd, count, A);
    refine_kernel<<<B_IMG, 1024, 0, stream>>>(bnd, state, cand, count);
    rankdecode_kernel<<<dim3(CAND_CAP / 256, B_IMG), 256, 0, stream>>>(
        cand, count, anchors, reg, boxes, X1, X2, Y1, Y2, AREA, s_top, A);
    mask_kernel<<<dim3(PRE_NMS * 64 / 256, B_IMG), 256, 0, stream>>>(X1, X2, Y1, Y2, AREA, mask);
    nms_select_kernel<<<B_IMG, 256, 0, stream>>>(mask, boxes, s_top, out);
}

// Round 9
// 359.475 us; speedup vs baseline: 1.2804x; 1.0282x over previous
//
#include <hip/hip_runtime.h>
#include <hip/hip_bf16.h>

#define B_IMG 4
#define PRE_NMS 4096
#define POST_NMS 500
#define CAND_CAP 8192
#define BND_CAP 65536
#define HBLK 64

typedef unsigned long long ull;

__device__ __forceinline__ unsigned key_of(float f) {
    unsigned u = __float_as_uint(f);
    return (u & 0x80000000u) ? ~u : (u | 0x80000000u);
}

// Raw barrier: orders LDS (lgkmcnt) but leaves global prefetches (vmcnt) in
// flight — __syncthreads() would emit s_waitcnt vmcnt(0) and drain the pipeline.
__device__ __forceinline__ void wave_barrier() {
    asm volatile("s_waitcnt lgkmcnt(0)" ::: "memory");
    __builtin_amdgcn_s_barrier();
    __builtin_amdgcn_sched_barrier(0);
}

// ---------------- pass-0 histogram (top byte), per-block partials ----------------
__global__ void hist0_kernel(const float* __restrict__ obj, unsigned* __restrict__ histPart, int A) {
    int b = blockIdx.y;
    __shared__ unsigned h[4][256];
    int t = threadIdx.x;
#pragma unroll
    for (int r = 0; r < 4; r++) h[r][t] = 0u;
    __syncthreads();
    const float4* o4 = (const float4*)(obj + (size_t)b * A);
    int n4 = A >> 2;
    int stride = gridDim.x * blockDim.x;
    int rep = t & 3;
    for (int i = blockIdx.x * blockDim.x + t; i < n4; i += stride) {
        float4 v = o4[i];
        atomicAdd(&h[rep][key_of(v.x) >> 24], 1u);
        atomicAdd(&h[rep][key_of(v.y) >> 24], 1u);
        atomicAdd(&h[rep][key_of(v.z) >> 24], 1u);
        atomicAdd(&h[rep][key_of(v.w) >> 24], 1u);
    }
    if (blockIdx.x == 0 && t < (A & 3)) {
        unsigned k = key_of(obj[(size_t)b * A + (A & ~3) + t]);
        atomicAdd(&h[rep][k >> 24], 1u);
    }
    __syncthreads();
    histPart[((size_t)b * HBLK + blockIdx.x) * 256 + t] = h[0][t] + h[1][t] + h[2][t] + h[3][t];
}

// ---------------- pass-0 reduce + boundary scan; zero counters ----------------
__global__ void __launch_bounds__(1024) scan0_kernel(uint2* state, const unsigned* __restrict__ histPart,
                                                     unsigned* __restrict__ count) {
    int b = blockIdx.x;
    int t = threadIdx.x;            // 1024: bin = t&255, chunk = t>>8 (4 chunks of 16 blocks)
    int bin = t & 255, ch = t >> 8;
    __shared__ unsigned part[4][256];
    __shared__ unsigned h[256];
    unsigned s = 0;
#pragma unroll
    for (int k = 0; k < HBLK / 4; k++)
        s += histPart[((size_t)b * HBLK + ch * (HBLK / 4) + k) * 256 + bin];
    part[ch][bin] = s;
    __syncthreads();
    if (t < 256) h[t] = part[0][t] + part[1][t] + part[2][t] + part[3][t];
    __syncthreads();
    if (t == 0) {
        unsigned kneed = PRE_NMS, cum = 0;
        int d;
        for (d = 255; d > 0; d--) {
            unsigned c = h[d];
            if (cum + c >= kneed) break;
            cum += c;
        }
        state[b] = make_uint2((unsigned)d, kneed - cum);
        count[b] = 0u;
        count[B_IMG + b] = 0u;
    }
}

// ---------------- compact: emit all elements with top byte >= d0 ----------------
__global__ void compact_kernel(const float* __restrict__ obj, const uint2* __restrict__ state,
                               ull* __restrict__ bnd, unsigned* __restrict__ count, int A) {
    int b = blockIdx.y;
    unsigned d0 = state[b].x;
    __shared__ ull buf[2048];
    __shared__ unsigned lcnt, base;
    int t = threadIdx.x;
    if (t == 0) lcnt = 0u;
    __syncthreads();
    const float4* o4 = (const float4*)(obj + (size_t)b * A);
    int n4 = A >> 2;
    int stride = gridDim.x * blockDim.x;
    for (int i = blockIdx.x * blockDim.x + t; i < n4; i += stride) {
        float4 v = o4[i];
        unsigned i0 = (unsigned)i * 4u;
        unsigned k0 = key_of(v.x), k1 = key_of(v.y), k2 = key_of(v.z), k3 = key_of(v.w);
        if ((k0 >> 24) >= d0) { unsigned p = atomicAdd(&lcnt, 1u); if (p < 2048u) buf[p] = ((ull)k0 << 32) | (0xFFFFFFFFu - i0); }
        if ((k1 >> 24) >= d0) { unsigned p = atomicAdd(&lcnt, 1u); if (p < 2048u) buf[p] = ((ull)k1 << 32) | (0xFFFFFFFFu - (i0 + 1u)); }
        if ((k2 >> 24) >= d0) { unsigned p = atomicAdd(&lcnt, 1u); if (p < 2048u) buf[p] = ((ull)k2 << 32) | (0xFFFFFFFFu - (i0 + 2u)); }
        if ((k3 >> 24) >= d0) { unsigned p = atomicAdd(&lcnt, 1u); if (p < 2048u) buf[p] = ((ull)k3 << 32) | (0xFFFFFFFFu - (i0 + 3u)); }
    }
    if (blockIdx.x == 0 && t < (A & 3)) {
        unsigned ii = (unsigned)(A & ~3) + t;
        unsigned k = key_of(obj[(size_t)b * A + ii]);
        if ((k >> 24) >= d0) { unsigned p = atomicAdd(&lcnt, 1u); if (p < 2048u) buf[p] = ((ull)k << 32) | (0xFFFFFFFFu - ii); }
    }
    __syncthreads();
    unsigned c = lcnt < 2048u ? lcnt : 2048u;
    if (t == 0) base = atomicAdd(&count[B_IMG + b], c);
    __syncthreads();
    for (unsigned p = t; p < c; p += blockDim.x) {
        unsigned pos = base + p;
        if (pos < BND_CAP) bnd[(size_t)b * BND_CAP + pos] = buf[p];
    }
}

// ---------------- refine: radix passes 1-3 + threshold gather + zero-pad ----------------
__global__ void __launch_bounds__(1024) refine_kernel(const ull* __restrict__ bnd,
                                                      const uint2* __restrict__ state,
                                                      ull* __restrict__ cand,
                                                      unsigned* __restrict__ count) {
    int b = blockIdx.x;
    __shared__ unsigned h[256];
    __shared__ unsigned sh_prefix, sh_kneed, sh_pos;
    int t = threadIdx.x;
    unsigned n = count[B_IMG + b];
    if (n > BND_CAP) n = BND_CAP;
    const ull* L = bnd + (size_t)b * BND_CAP;
    if (t == 0) { sh_prefix = state[b].x; sh_kneed = state[b].y; sh_pos = 0u; }
    for (int pass = 1; pass < 4; pass++) {
        if (t < 256) h[t] = 0u;
        __syncthreads();
        unsigned prefix = sh_prefix;
        int sh = 32 - 8 * pass, dsh = 24 - 8 * pass;
        for (unsigned i = t; i < n; i += 1024) {
            unsigned key = (unsigned)(L[i] >> 32);
            if ((key >> sh) == prefix) atomicAdd(&h[(key >> dsh) & 255u], 1u);
        }
        __syncthreads();
        if (t == 0) {
            unsigned kneed = sh_kneed, cum = 0;
            int d;
            for (d = 255; d > 0; d--) {
                unsigned c = h[d];
                if (cum + c >= kneed) break;
                cum += c;
            }
            sh_prefix = (prefix << 8) | (unsigned)d;
            sh_kneed = kneed - cum;
        }
        __syncthreads();
    }
    unsigned T = sh_prefix;
    for (unsigned i = t; i < n; i += 1024) {
        ull v = L[i];
        if ((unsigned)(v >> 32) >= T) {
            unsigned p = atomicAdd(&sh_pos, 1u);
            if (p < CAND_CAP) cand[(size_t)b * (CAND_CAP + 16) + p] = v;
        }
    }
    __syncthreads();
    if (t < 16) {
        unsigned cc = sh_pos < CAND_CAP ? sh_pos : CAND_CAP;
        cand[(size_t)b * (CAND_CAP + 16) + cc + t] = 0ull;  // zero-pad for rank's 16-unroll
        if (t == 0) count[b] = cc;
    }
}

// ---------------- rank + decode fused (LDS-staged) ----------------
__global__ void __launch_bounds__(256) rankdecode_kernel(
        const ull* __restrict__ cand, const unsigned* __restrict__ count,
        const float* __restrict__ anchors, const float* __restrict__ reg,
        float* __restrict__ boxes, float* __restrict__ X1, float* __restrict__ X2,
        float* __restrict__ Y1, float* __restrict__ Y2, float* __restrict__ AREA,
        float* __restrict__ s_top, int A) {
    __shared__ ull s[CAND_CAP];
    int b = blockIdx.y;
    unsigned cnt = count[b];
    if (cnt > CAND_CAP) cnt = CAND_CAP;
    if (blockIdx.x * 256 >= cnt) return;          // uniform: whole block idle
    int t = threadIdx.x;
    const ull* C = cand + (size_t)b * (CAND_CAP + 16);
    unsigned cntR = (cnt + 15u) & ~15u;           // pad covered by 16 zero-pads
    for (unsigned i = t; i < cntR; i += 256) s[i] = C[i];
    __syncthreads();
    unsigned c = blockIdx.x * 256 + t;
    if (c >= cnt) return;
    ull me = s[c];
    unsigned rank = 0;
    for (unsigned j = 0; j < cntR; j += 16) {
#pragma unroll
        for (int k = 0; k < 16; k++) rank += (unsigned)(s[j + k] > me);
    }
    if (rank >= PRE_NMS) return;
    unsigned key = (unsigned)(me >> 32);
    unsigned idx = 0xFFFFFFFFu - (unsigned)(me & 0xFFFFFFFFull);
    unsigned ub = (key & 0x80000000u) ? (key & 0x7FFFFFFFu) : ~key;
    float x = __uint_as_float(ub);
    s_top[b * PRE_NMS + rank] = 1.0f / (1.0f + expf(-x));
    const float* an = anchors + ((size_t)b * A + idx) * 7;
    const float* rg = reg + ((size_t)b * A + idx) * 7;
    float xa = an[0], ya = an[1], za = an[2], wa = an[3], la = an[4], ha = an[5], ra = an[6];
    float diagv = sqrtf(wa * wa + la * la);
    float xg = rg[0] * diagv + xa;
    float yg = rg[1] * diagv + ya;
    float zg = rg[2] * ha + za;
    float wg = expf(rg[3]) * wa;
    float lg = expf(rg[4]) * la;
    float hg = expf(rg[5]) * ha;
    float rr = rg[6] + ra;
    float* o = boxes + ((size_t)b * PRE_NMS + rank) * 7;
    o[0] = xg; o[1] = yg; o[2] = zg; o[3] = wg; o[4] = lg; o[5] = hg; o[6] = rr;
    int q = b * PRE_NMS + rank;
    X1[q] = xg - wg * 0.5f;
    X2[q] = xg + wg * 0.5f;
    Y1[q] = yg - lg * 0.5f;
    Y2[q] = yg + lg * 0.5f;
    AREA[q] = wg * lg;
}

// ---------------- suppression bitmask (triangular early-out) ----------------
__global__ void mask_kernel(const float* __restrict__ X1, const float* __restrict__ X2,
                            const float* __restrict__ Y1, const float* __restrict__ Y2,
                            const float* __restrict__ AREA, ull* __restrict__ mask) {
    int b = blockIdx.y;
    int t = blockIdx.x * 256 + threadIdx.x;
    int i = t & (PRE_NMS - 1);
    int w = t >> 12;
    size_t mi = ((size_t)b * PRE_NMS + i) * 64 + w;
    if (i >= ((w + 1) << 6)) { mask[mi] = 0ull; return; }  // all j<=i -> word is 0
    int q0 = b * PRE_NMS;
    float x1i = X1[q0 + i], x2i = X2[q0 + i];
    float y1i = Y1[q0 + i], y2i = Y2[q0 + i];
    float ai = AREA[q0 + i];
    ull word = 0ull;
    int jbase = w << 6;
#pragma unroll 4
    for (int k = 0; k < 64; k++) {
        int j = jbase + k;
        float iw = fminf(x2i, X2[q0 + j]) - fmaxf(x1i, X1[q0 + j]);
        iw = fmaxf(iw, 0.0f);
        float ih = fminf(y2i, Y2[q0 + j]) - fmaxf(y1i, Y1[q0 + j]);
        ih = fmaxf(ih, 0.0f);
        float inter = iw * ih;
        float den = ai + AREA[q0 + j] - inter + 1e-6f;
        float iou = inter / den;
        word |= ((ull)((iou > 0.7f) && (j > i))) << k;
    }
    mask[mi] = word;
}

// ---------------- 4-wave cooperative NMS + select + write ----------------
// Raw barriers keep the depth-4 global prefetch in flight (no vmcnt drain).
// Loads predicated on lane >= tile (lower-triangle words are zero by construction).
__global__ void __launch_bounds__(256, 1) nms_select_kernel(
        const ull* __restrict__ mask, const float* __restrict__ boxes,
        const float* __restrict__ s_top, float* __restrict__ out) {
    int b = blockIdx.x;
    int t = threadIdx.x;
    int lane = t & 63, v = t >> 6;
    int rbase = v * 16;
    const ull* Mb = mask + (size_t)b * PRE_NMS * 64;
    __shared__ ull diag[2][64];
    __shared__ ull part[2][4][64];
    __shared__ ull keepw[64];
    __shared__ int cnts[64];
    __shared__ int bases[65];
    __shared__ int sel[POST_NMS];
    ull K = ~0ull;
    ull b0[16], b1[16], b2[16], b3[16];

#define PREF(W, BUF) do {                                                          \
    if (lane >= (W)) {                                                             \
        _Pragma("unroll")                                                          \
        for (int kk = 0; kk < 16; kk++)                                            \
            BUF[kk] = Mb[(((size_t)(W) * 64 + rbase + kk) << 6) + lane];           \
    } else {                                                                       \
        _Pragma("unroll")                                                          \
        for (int kk = 0; kk < 16; kk++) BUF[kk] = 0ull;                            \
    }                                                                              \
} while (0)

#define TILE(W, BUF) do {                                                          \
    int par = (W) & 1;                                                             \
    ull cur = __shfl(K, (W));                                                      \
    if (lane == (W)) {                                                             \
        _Pragma("unroll")                                                          \
        for (int kk = 0; kk < 16; kk++) diag[par][rbase + kk] = BUF[kk];           \
    }                                                                              \
    wave_barrier();                                                                \
    ull dl = diag[par][lane];                                                      \
    ull active = __ballot(dl != 0ull) & cur;                                       \
    while (active) {                                                               \
        int kk = __ffsll((long long)active) - 1;                                   \
        ull dk = __shfl(dl, kk);                                                   \
        cur &= ~dk; active &= ~dk; active &= ~(1ull << kk);                        \
    }                                                                              \
    ull sup = 0ull;                                                                \
    _Pragma("unroll")                                                              \
    for (int kk = 0; kk < 16; kk++)                                                \
        sup |= ((cur >> (rbase + kk)) & 1ull) ? BUF[kk] : 0ull;                    \
    part[par][v][lane] = sup;                                                      \
    if ((W) + 4 < 64) PREF((W) + 4, BUF);   /* issue before barrier2 */            \
    wave_barrier();                                                                \
    K &= ~(part[par][0][lane] | part[par][1][lane] |                               \
           part[par][2][lane] | part[par][3][lane]);                               \
} while (0)

    PREF(0, b0); PREF(1, b1); PREF(2, b2); PREF(3, b3);
    for (int w = 0; w < 64; w += 4) {
        TILE(w + 0, b0);
        TILE(w + 1, b1);
        TILE(w + 2, b2);
        TILE(w + 3, b3);
    }
#undef PREF
#undef TILE

    if (v == 0) keepw[lane] = K;
    __syncthreads();
    if (t < 64) cnts[t] = __popcll(keepw[t]);
    __syncthreads();
    if (t == 0) {
        int acc = 0;
        for (int w = 0; w < 64; w++) { bases[w] = acc; acc += cnts[w]; }
        bases[64] = acc;
    }
    __syncthreads();
    if (t < 64) {
        ull kw = keepw[t];
        int K_total = bases[64];
        int kr = bases[t];
        int ur = t * 64 - bases[t];
        for (int k = 0; k < 64; k++) {
            int i = t * 64 + k;
            if ((kw >> k) & 1ull) {
                if (kr < POST_NMS) sel[kr] = i;
                kr++;
            } else {
                int pos = K_total + ur;
                if (pos < POST_NMS) sel[pos] = i;
                ur++;
            }
        }
    }
    __syncthreads();
    for (int r = t; r < POST_NMS; r += 256) {
        int i = sel[r];
        const float* bx = boxes + ((size_t)b * PRE_NMS + i) * 7;
        float* o = out + ((size_t)b * POST_NMS + r) * 8;
#pragma unroll
        for (int c = 0; c < 7; c++) o[c] = bx[c];
        o[7] = s_top[b * PRE_NMS + i];
    }
}

extern "C" void kernel_launch(void* const* d_in, const int* in_sizes, int n_in,
                              void* d_out, int out_size, void* d_ws, size_t ws_size,
                              hipStream_t stream) {
    const float* anchors = (const float*)d_in[0];
    const float* obj = (const float*)d_in[1];
    const float* reg = (const float*)d_in[2];
    float* out = (float*)d_out;
    const int A = in_sizes[1] / B_IMG;

    auto align = [](size_t x) { return (x + 255) & ~(size_t)255; };
    char* p = (char*)d_ws;
    uint2* state = (uint2*)p;       p += align(B_IMG * sizeof(uint2));
    unsigned* histPart = (unsigned*)p; p += align((size_t)B_IMG * HBLK * 256 * 4);
    unsigned* count = (unsigned*)p; p += align(2 * B_IMG * sizeof(unsigned));
    ull* cand = (ull*)p;            p += align((size_t)B_IMG * (CAND_CAP + 16) * 8);
    ull* bnd = (ull*)p;             p += align((size_t)B_IMG * BND_CAP * 8);
    float* s_top = (float*)p;       p += align((size_t)B_IMG * PRE_NMS * 4);
    float* boxes = (float*)p;       p += align((size_t)B_IMG * PRE_NMS * 7 * 4);
    float* X1 = (float*)p;          p += align((size_t)B_IMG * PRE_NMS * 4);
    float* X2 = (float*)p;          p += align((size_t)B_IMG * PRE_NMS * 4);
    float* Y1 = (float*)p;          p += align((size_t)B_IMG * PRE_NMS * 4);
    float* Y2 = (float*)p;          p += align((size_t)B_IMG * PRE_NMS * 4);
    float* AREA = (float*)p;        p += align((size_t)B_IMG * PRE_NMS * 4);
    ull* mask = (ull*)p;            p += align((size_t)B_IMG * PRE_NMS * 64 * 8);

    hist0_kernel<<<dim3(HBLK, B_IMG), 256, 0, stream>>>(obj, histPart, A);
    scan0_kernel<<<B_IMG, 1024, 0, stream>>>(state, histPart, count);
    compact_kernel<<<dim3(HBLK, B_IMG), 256, 0, stream>>>(obj, state, bnd, count, A);
    refine_kernel<<<B_IMG, 1024, 0, stream>>>(bnd, state, cand, count);
    rankdecode_kernel<<<dim3(CAND_CAP / 256, B_IMG), 256, 0, stream>>>(
        cand, count, anchors, reg, boxes, X1, X2, Y1, Y2, AREA, s_top, A);
    mask_kernel<<<dim3(PRE_NMS * 64 / 256, B_IMG), 256, 0, stream>>>(X1, X2, Y1, Y2, AREA, mask);
    nms_select_kernel<<<B_IMG, 256, 0, stream>>>(mask, boxes, s_top, out);
}